// Round 14
// baseline (345.693 us; speedup 1.0000x reference)
//
#include <hip/hip_runtime.h>
#include <hip/hip_bf16.h>
#include <math.h>

#define BB 16
#define CC 32
#define NN 300
#define TT 12
#define STF 40
#define DHD 16
#define COO 32
#define NCH 4
#define COL 96
#define NIB 64          // NCH*BB
#define KP  320         // padded K / node dim
#define ALPHAF 0.05f
#define HS 40           // hst inner stride (halfwords): 80B, 16B-aligned, 2-way bank alias (free)
#define ATILES 40       // k_adj row tiles (covers all 320 rows incl. zero pad)

typedef __attribute__((ext_vector_type(8))) short short8;   // 8 bf16 (4 VGPRs)
typedef __attribute__((ext_vector_type(4))) float f32x4;    // MFMA 16x16 accumulator
typedef unsigned short ushort_t;

// ---- workspace layout (float units), total 9,853,952 floats = 39.4 MB (ws >= 45.5 MB proven) ----
#define O_INP   0           // 614400   [ib][n][c] fp32
#define O_XVB   614400      // 921600   bf16 [ib][300][96]  (A-side / epilogue x)
#define O_GA1   1536000     // 307200 each, [ib][n][d] fp32
#define O_GB1   1843200
#define O_GA2   2150400
#define O_GB2   2457600
#define O_ADJB  2764800     // bf16 [ib][320][320]
#define O_XTB   6041600     // bf16 [ib][96][320]  (B-side conv1)
#define O_H1B   7024640     // bf16 [ib][96][320]  (B-side conv2)
#define O_H1VB  8007680     // bf16 [ib][300][96]  (A-side MLP depth-1)
#define O_WMB   8929280     // bf16 [32][96]       (B-side MLP)
#define O_IRZ   8932352     // 614400  [ib][n][32]  inp@W_rz[:32] + b_rz
#define O_IH    9546752     // 307200  [ib][n][16]  inp@W_h[:32] + b_h

__device__ __forceinline__ float sigf(float x){ return 1.0f/(1.0f+expf(-x)); }

// x (B,C,N,T) -> inp (t-means), xtb [ib][col][320] bf16, xvb [ib][n][col] bf16
// + zero-fill K-pad of xtb/h1b + build Wmb
__global__ void k_prep(const float* __restrict__ x, __hip_bfloat16* __restrict__ xtb,
                       __hip_bfloat16* __restrict__ xvb, float* __restrict__ inp,
                       __hip_bfloat16* __restrict__ h1b, const float* __restrict__ Wm,
                       __hip_bfloat16* __restrict__ Wmb){
    int idx = blockIdx.x*256 + threadIdx.x;   // (b,c,n), n fastest
    if (idx >= BB*CC*NN) return;
    // side jobs on low threads
    if (idx < NIB*COL*(KP-NN)){               // 122880: zero K-pads
        int kk  = idx % (KP-NN);
        int col = (idx / (KP-NN)) % COL;
        int ib  = idx / ((KP-NN)*COL);
        size_t off = ((size_t)ib*COL + col)*KP + NN + kk;
        xtb[off] = __float2bfloat16(0.0f);
        h1b[off] = __float2bfloat16(0.0f);
    }
    if (idx < COO*COL){                       // 3072: Wmb[o][k] = Wm[k][o]
        int o = idx / COL, k = idx % COL;
        Wmb[o*COL + k] = __float2bfloat16(Wm[k*COO + o]);
    }
    int n = idx % NN;
    int c = (idx / NN) % CC;
    int b = idx / (NN*CC);
    const float* xp = x + ((b*CC + c)*NN + n)*TT;
    float v[TT];
    #pragma unroll
    for (int t=0;t<TT;t++) v[t] = xp[t];
    #pragma unroll
    for (int i=0;i<NCH;i++){
        float m = (v[3*i]+v[3*i+1]+v[3*i+2])*(1.0f/3.0f);
        int ib = i*BB + b;
        inp[((size_t)ib*NN + n)*CC + c] = m;
        #pragma unroll
        for (int t=0;t<3;t++){
            float val = v[3*i+t];
            int col = c*3 + t;
            xtb[((size_t)ib*COL + col)*KP + n] = __float2bfloat16(val);
            xvb[((size_t)ib*NN + n)*COL + col] = __float2bfloat16(val);
        }
    }
}

// inp-part projections: irz[rowg][j] = inp[rowg]@W_rz[:32][:,j] + b_rz[j]   (j<32)
//                       ih [rowg][d] = inp[rowg]@W_h [:32][:,d] + b_h[d]    (d<16)
__global__ void k_iproj(const float* __restrict__ inp,
                        const float* __restrict__ W_rz, const float* __restrict__ b_rz,
                        const float* __restrict__ W_h,  const float* __restrict__ b_h,
                        float* __restrict__ irz, float* __restrict__ ih){
    int idx = blockIdx.x*256 + threadIdx.x;
    if (idx >= NCH*BB*NN*48) return;
    int j    = idx % 48;
    int rowg = idx / 48;                       // ib*NN + n
    const float* ip = inp + (size_t)rowg*CC;
    float a0=0.f,a1=0.f,a2=0.f,a3=0.f;
    if (j < 32){
        #pragma unroll
        for (int k=0;k<32;k+=4){
            a0 += ip[k  ]*W_rz[(k  )*32+j];
            a1 += ip[k+1]*W_rz[(k+1)*32+j];
            a2 += ip[k+2]*W_rz[(k+2)*32+j];
            a3 += ip[k+3]*W_rz[(k+3)*32+j];
        }
        irz[(size_t)rowg*32 + j] = a0+a1+a2+a3 + b_rz[j];
    } else {
        int d = j-32;
        #pragma unroll
        for (int k=0;k<32;k+=4){
            a0 += ip[k  ]*W_h[(k  )*DHD+d];
            a1 += ip[k+1]*W_h[(k+1)*DHD+d];
            a2 += ip[k+2]*W_h[(k+2)*DHD+d];
            a3 += ip[k+3]*W_h[(k+3)*DHD+d];
        }
        ih[(size_t)rowg*DHD + d] = a0+a1+a2+a3 + b_h[d];
    }
}

// fused: init state + 4 GRU steps + edge projections. 1 wave per (b,n) row.
// Pure-shuffle implementation: NO LDS, NO barriers -> race-free by construction.
// State st_d replicated in every lane with d = tid&15.
__global__ __launch_bounds__(64) void k_gru_all(
        const float* __restrict__ stnf, const float* __restrict__ W_s2d,
        const float* __restrict__ b_s2d,
        const float* __restrict__ irz, const float* __restrict__ ih,
        const float* __restrict__ W_rz, const float* __restrict__ W_h,
        const float* __restrict__ Wc1,  const float* __restrict__ Wc2,
        float* __restrict__ ga1, float* __restrict__ gb1,
        float* __restrict__ ga2, float* __restrict__ gb2){
    int row = blockIdx.x;          // b*NN + n
    int n   = row % NN;
    int tid = threadIdx.x;         // 0..63
    int d   = tid & 15;
    // role-based state-part weight columns (registers)
    float wst[16];
    if (tid < 32){
        #pragma unroll
        for (int k=0;k<16;k++) wst[k] = W_rz[(32+k)*32 + tid];
    } else if (tid < 48){
        #pragma unroll
        for (int k=0;k<16;k++) wst[k] = W_h[(32+k)*DHD + d];
    } else {
        #pragma unroll
        for (int k=0;k<16;k++) wst[k] = 0.0f;
    }
    // projection weight column (all lanes)
    float wpj[16];
    {
        int which = tid >> 4;
        const float* W = (which < 2) ? Wc1 : Wc2;
        int off = (which & 1) ? 16*DHD : 0;
        #pragma unroll
        for (int k=0;k<16;k++) wpj[k] = W[off + k*DHD + d];
    }
    // init state (replicated: every lane computes st for its d)
    float st = b_s2d[d];
    {
        const float* srow = stnf + n*STF;
        #pragma unroll
        for (int k=0;k<STF;k++) st += srow[k]*W_s2d[k*DHD + d];
    }
    for (int i=0;i<NCH;i++){
        size_t rowg = (size_t)i*BB*NN + row;
        float ibase = (tid < 32) ? irz[rowg*32 + tid]
                    : (tid < 48) ? ih[rowg*DHD + d] : 0.0f;
        // phase 1: rz (meaningful on lanes 0..31; lane j computes rz_j)
        float acc = ibase;
        #pragma unroll
        for (int k=0;k<16;k++) acc += __shfl(st, k) * wst[k];
        float rz = sigf(acc);            // lanes 0-15: r_d ; lanes 16-31: z_d
        // phase 2: h (meaningful on lanes 32..47)
        float acc2 = ibase;
        #pragma unroll
        for (int k=0;k<16;k++) acc2 += __shfl(rz, k) * __shfl(st, k) * wst[k];
        float hh = tanhf(acc2);          // lanes 32-47: h_d
        // phase 3: state update on all lanes (replicated)
        float z  = __shfl(rz, 16 + d);
        float hd = __shfl(hh, 32 + d);
        st = z*st + (1.0f - z)*hd;
        float hs = fmaxf(st, 0.0f);
        // phase 4: edge projections (lane group = which matrix, d = column)
        float acc3 = 0.0f;
        #pragma unroll
        for (int k=0;k<16;k++) acc3 += __shfl(hs, k) * wpj[k];
        int which = tid >> 4;
        float* dst = (which==0)? ga1 : (which==1)? gb1 : (which==2)? ga2 : gb2;
        dst[rowg*DHD + d] = acc3;
    }
}

// grid = NIB*ATILES; adjb bf16 [ib][320][320]; rows/cols in [300,320) zero-filled
__global__ void k_adj(const float* __restrict__ ga1, const float* __restrict__ gb1,
                      const float* __restrict__ ga2, const float* __restrict__ gb2,
                      const float* __restrict__ bfc2_1, const float* __restrict__ wfc1_1, const float* __restrict__ bfc1_1,
                      const float* __restrict__ bfc2_2, const float* __restrict__ wfc1_2, const float* __restrict__ bfc1_2,
                      __hip_bfloat16* __restrict__ adjb){
    int tile = blockIdx.x % ATILES;
    int ib   = blockIdx.x / ATILES;
    int v0 = tile * 8;
    int tid = threadIdx.x;  // 256
    __shared__ float a1[8][16], a2[8][16];
    __shared__ float w1[16], w2[16];
    if (tid < 16) w1[tid] = wfc1_1[tid];
    else if (tid < 32) w2[tid-16] = wfc1_2[tid-16];
    {
        int vl = tid >> 5, which = (tid >> 4) & 1, k = tid & 15;
        int v = v0 + vl;
        float val = 0.0f;
        if (v < NN)
            val = which ? (ga2[((size_t)ib*NN+v)*DHD + k] + bfc2_2[k])
                        : (ga1[((size_t)ib*NN+v)*DHD + k] + bfc2_1[k]);
        if (which) a2[vl][k] = val; else a1[vl][k] = val;
    }
    float B1 = bfc1_1[0], B2 = bfc1_2[0];
    __syncthreads();
    const __hip_bfloat16 ZB = __float2bfloat16(0.0f);
    for (int w = tid; w < KP; w += 256){
        if (w < NN){
            const float4* p1 = (const float4*)(gb1 + ((size_t)ib*NN + w)*DHD);
            const float4* p2 = (const float4*)(gb2 + ((size_t)ib*NN + w)*DHD);
            float4 A[4], Bv[4];
            #pragma unroll
            for (int q=0;q<4;q++){ A[q]=p1[q]; Bv[q]=p2[q]; }
            const float* g1 = (const float*)A;
            const float* g2 = (const float*)Bv;
            #pragma unroll
            for (int vl=0; vl<8; vl++){
                int v = v0 + vl;
                if (v < NN){
                    float s = B1, m = B2;
                    #pragma unroll
                    for (int k=0;k<16;k++){
                        s += fmaxf(a1[vl][k] + g1[k], 0.0f)*w1[k];
                        m += fmaxf(a2[vl][k] + g2[k], 0.0f)*w2[k];
                    }
                    adjb[((size_t)ib*KP + v)*KP + w] = __float2bfloat16(s * sigf(m));
                } else {
                    adjb[((size_t)ib*KP + v)*KP + w] = ZB;
                }
            }
        } else {
            #pragma unroll
            for (int vl=0; vl<8; vl++){
                int v = v0 + vl;
                adjb[((size_t)ib*KP + v)*KP + w] = ZB;
            }
        }
    }
}

// MFMA conv core: block = 4 waves, output tile 32 v-rows x 96 cols, K=320.
// A: adjb[ib][v][k] (row=l&15, k=8*(l>>4)+j) ; B: Hb[ib][col][k] ; D: col=l&15, row=(l>>4)*4+reg
__device__ __forceinline__ void conv_mfma_tile(const __hip_bfloat16* __restrict__ adjb,
                                               const __hip_bfloat16* __restrict__ Hb,
                                               int ib, int v0, int wave, int lane,
                                               f32x4& acc0, f32x4& acc1, f32x4& acc2){
    int l15 = lane & 15, lk = lane >> 4;
    int wrow = (wave & 1) * 16;
    int wcol = (wave >> 1) * 48;
    const short8* Ap  = (const short8*)(adjb + ((size_t)ib*KP + v0 + wrow + l15)*KP + 8*lk);
    const short8* Bp0 = (const short8*)(Hb   + ((size_t)ib*COL + wcol +  0 + l15)*KP + 8*lk);
    const short8* Bp1 = (const short8*)(Hb   + ((size_t)ib*COL + wcol + 16 + l15)*KP + 8*lk);
    const short8* Bp2 = (const short8*)(Hb   + ((size_t)ib*COL + wcol + 32 + l15)*KP + 8*lk);
    #pragma unroll 2
    for (int kk=0; kk<KP/32; kk++){
        short8 a = Ap[kk*4];
        acc0 = __builtin_amdgcn_mfma_f32_16x16x32_bf16(a, Bp0[kk*4], acc0, 0, 0, 0);
        acc1 = __builtin_amdgcn_mfma_f32_16x16x32_bf16(a, Bp1[kk*4], acc1, 0, 0, 0);
        acc2 = __builtin_amdgcn_mfma_f32_16x16x32_bf16(a, Bp2[kk*4], acc2, 0, 0, 0);
    }
}

// grid = NIB*10. h1 = 0.05*x + 0.95*(adj @ x); writes h1b [col][320] and h1vb [v][96]
__global__ __launch_bounds__(256) void k_conv1(const __hip_bfloat16* __restrict__ adjb,
                                               const __hip_bfloat16* __restrict__ xtb,
                                               const __hip_bfloat16* __restrict__ xvb,
                                               __hip_bfloat16* __restrict__ h1b,
                                               __hip_bfloat16* __restrict__ h1vb){
    int ib = blockIdx.x / 10;
    int v0 = (blockIdx.x % 10) * 32;
    int tid = threadIdx.x;
    int wave = tid >> 6, lane = tid & 63;
    int l15 = lane & 15, lk = lane >> 4;
    int wrow = (wave & 1) * 16;
    int wcol = (wave >> 1) * 48;
    __shared__ float hbuf[COL][33];
    f32x4 acc0 = {0.f,0.f,0.f,0.f}, acc1 = acc0, acc2 = acc0;
    conv_mfma_tile(adjb, xtb, ib, v0, wave, lane, acc0, acc1, acc2);
    f32x4 accs[3] = {acc0, acc1, acc2};
    #pragma unroll
    for (int t=0;t<3;t++){
        int col = wcol + t*16 + l15;
        #pragma unroll
        for (int r=0;r<4;r++){
            int vloc = wrow + lk*4 + r;
            int v = v0 + vloc;
            float xval = (v < NN) ? __bfloat162float(xvb[((size_t)ib*NN + v)*COL + col]) : 0.0f;
            hbuf[col][vloc] = ALPHAF*xval + (1.0f-ALPHAF)*accs[t][r];
        }
    }
    __syncthreads();
    for (int idx = tid; idx < COL*32; idx += 256){
        int col = idx >> 5, vloc = idx & 31;
        int v = v0 + vloc;
        if (v < NN)
            h1b[((size_t)ib*COL + col)*KP + v] = __float2bfloat16(hbuf[col][vloc]);
    }
    for (int idx = tid; idx < 32*COL; idx += 256){
        int vloc = idx / COL, col = idx % COL;
        int v = v0 + vloc;
        if (v < NN)
            h1vb[((size_t)ib*NN + v)*COL + col] = __float2bfloat16(hbuf[col][vloc]);
    }
}

// grid = NIB*10. h2 = 0.05*x + 0.95*(adj @ h1); MLP done as MFMA (12 tiles, K=96).
__global__ __launch_bounds__(256) void k_conv2_mlp(const __hip_bfloat16* __restrict__ adjb,
                                                   const __hip_bfloat16* __restrict__ h1b,
                                                   const __hip_bfloat16* __restrict__ xvb,
                                                   const __hip_bfloat16* __restrict__ h1vb,
                                                   const __hip_bfloat16* __restrict__ Wmb,
                                                   const float* __restrict__ bmlp,
                                                   float* __restrict__ out){
    int ib = blockIdx.x / 10;
    int v0 = (blockIdx.x % 10) * 32;
    int b  = ib % BB, chunk = ib / BB;
    int tid = threadIdx.x;
    int wave = tid >> 6, lane = tid & 63;
    int l15 = lane & 15, lk = lane >> 4;
    int wrow = (wave & 1) * 16;
    int wcol = (wave >> 1) * 48;
    __shared__ ushort_t hst[3][3][32][HS];   // [t][depth][v][c]  bf16 bits
    // stage h0 (x) and h1 into hst while conv MFMAs run
    for (int idx = tid; idx < 2*32*COL; idx += 256){
        int which = idx / (32*COL);
        int r     = idx % (32*COL);
        int vloc  = r / COL, col = r % COL;
        int v = v0 + vloc;
        int c = col/3, t = col%3;
        ushort_t val = 0;
        if (v < NN){
            const ushort_t* src = (const ushort_t*)(which ? h1vb : xvb);
            val = src[((size_t)ib*NN + v)*COL + col];
        }
        hst[t][which][vloc][c] = val;
    }
    f32x4 acc0 = {0.f,0.f,0.f,0.f}, acc1 = acc0, acc2 = acc0;
    conv_mfma_tile(adjb, h1b, ib, v0, wave, lane, acc0, acc1, acc2);
    f32x4 accs[3] = {acc0, acc1, acc2};
    // h2 into hst
    #pragma unroll
    for (int tt=0;tt<3;tt++){
        int col = wcol + tt*16 + l15;
        int c = col/3, t = col%3;
        #pragma unroll
        for (int r=0;r<4;r++){
            int vloc = wrow + lk*4 + r;
            int v = v0 + vloc;
            float val = 0.0f;
            if (v < NN){
                float xval = __bfloat162float(xvb[((size_t)ib*NN + v)*COL + col]);
                val = ALPHAF*xval + (1.0f-ALPHAF)*accs[tt][r];
            }
            __hip_bfloat16 bv = __float2bfloat16(val);
            hst[t][2][vloc][c] = *(ushort_t*)&bv;
        }
    }
    __syncthreads();
    // MLP MFMA: tiles (t, vt, ot); wave handles tile ids wave, wave+4, wave+8
    #pragma unroll
    for (int j=0;j<3;j++){
        int tile = wave + 4*j;
        int t  = tile >> 2;
        int vt = (tile & 3) >> 1;
        int ot = tile & 1;
        f32x4 acc = {0.f,0.f,0.f,0.f};
        #pragma unroll
        for (int d=0;d<3;d++){
            short8 a = *(const short8*)&hst[t][d][vt*16 + l15][8*lk];
            short8 bfr = *(const short8*)(Wmb + ((size_t)(ot*16 + l15))*COL + d*32 + 8*lk);
            acc = __builtin_amdgcn_mfma_f32_16x16x32_bf16(a, bfr, acc, 0, 0, 0);
        }
        int o = ot*16 + l15;
        float bias = bmlp[o];
        #pragma unroll
        for (int r=0;r<4;r++){
            int v = v0 + vt*16 + lk*4 + r;
            if (v < NN)
                out[(((size_t)b*COO + o)*NN + v)*TT + chunk*3 + t] = acc[r] + bias;
        }
    }
}

extern "C" void kernel_launch(void* const* d_in, const int* in_sizes, int n_in,
                              void* d_out, int out_size, void* d_ws, size_t ws_size,
                              hipStream_t stream){
    const float* x     = (const float*)d_in[0];
    const float* stnf  = (const float*)d_in[1];
    const float* W_s2d = (const float*)d_in[2];
    const float* b_s2d = (const float*)d_in[3];
    const float* W_rz  = (const float*)d_in[4];
    const float* b_rz  = (const float*)d_in[5];
    const float* W_h   = (const float*)d_in[6];
    const float* b_h   = (const float*)d_in[7];
    const float* Wc1f2 = (const float*)d_in[8];
    const float* bc1f2 = (const float*)d_in[9];
    const float* Wc1f1 = (const float*)d_in[10];
    const float* bc1f1 = (const float*)d_in[11];
    const float* Wc2f2 = (const float*)d_in[12];
    const float* bc2f2 = (const float*)d_in[13];
    const float* Wc2f1 = (const float*)d_in[14];
    const float* bc2f1 = (const float*)d_in[15];
    const float* W_mlp = (const float*)d_in[16];
    const float* b_mlp = (const float*)d_in[17];
    float* out = (float*)d_out;
    float* ws  = (float*)d_ws;

    float* inp = ws + O_INP;
    float* ga1 = ws + O_GA1;
    float* gb1 = ws + O_GB1;
    float* ga2 = ws + O_GA2;
    float* gb2 = ws + O_GB2;
    float* irz = ws + O_IRZ;
    float* ih  = ws + O_IH;
    __hip_bfloat16* xvb  = (__hip_bfloat16*)(ws + O_XVB);
    __hip_bfloat16* adjb = (__hip_bfloat16*)(ws + O_ADJB);
    __hip_bfloat16* xtb  = (__hip_bfloat16*)(ws + O_XTB);
    __hip_bfloat16* h1b  = (__hip_bfloat16*)(ws + O_H1B);
    __hip_bfloat16* h1vb = (__hip_bfloat16*)(ws + O_H1VB);
    __hip_bfloat16* Wmb  = (__hip_bfloat16*)(ws + O_WMB);

    hipLaunchKernelGGL(k_prep, dim3(600), dim3(256), 0, stream, x, xtb, xvb, inp, h1b, W_mlp, Wmb);
    hipLaunchKernelGGL(k_iproj, dim3(3600), dim3(256), 0, stream,
                       inp, W_rz, b_rz, W_h, b_h, irz, ih);
    hipLaunchKernelGGL(k_gru_all, dim3(BB*NN), dim3(64), 0, stream,
                       stnf, W_s2d, b_s2d, irz, ih, W_rz, W_h, Wc1f2, Wc2f2,
                       ga1, gb1, ga2, gb2);
    hipLaunchKernelGGL(k_adj, dim3(NIB*ATILES), dim3(256), 0, stream,
                       ga1, gb1, ga2, gb2,
                       bc1f2, Wc1f1, bc1f1, bc2f2, Wc2f1, bc2f1, adjb);
    hipLaunchKernelGGL(k_conv1, dim3(NIB*10), dim3(256), 0, stream,
                       adjb, xtb, xvb, h1b, h1vb);
    hipLaunchKernelGGL(k_conv2_mlp, dim3(NIB*10), dim3(256), 0, stream,
                       adjb, h1b, xvb, h1vb, Wmb, b_mlp, out);
}

// Round 15
// 231.406 us; speedup vs baseline: 1.4939x; 1.4939x over previous
//
#include <hip/hip_runtime.h>
#include <hip/hip_bf16.h>
#include <math.h>

#define BB 16
#define CC 32
#define NN 300
#define TT 12
#define STF 40
#define DHD 16
#define COO 32
#define NCH 4
#define COL 96
#define NIB 64          // NCH*BB
#define KP  320         // padded K / node dim
#define ALPHAF 0.05f
#define HS 40           // hst inner stride (halfwords)
#define ATILES 40       // k_adj row tiles (covers all 320 rows incl. zero pad)

typedef __attribute__((ext_vector_type(8))) short short8;   // 8 bf16 (4 VGPRs)
typedef __attribute__((ext_vector_type(4))) float f32x4;    // MFMA 16x16 accumulator
typedef unsigned short ushort_t;

// ---- workspace layout (float units), total 9,853,952 floats = 39.4 MB ----
#define O_INP   0           // 614400   [ib][n][c] fp32
#define O_XVB   614400      // 921600   bf16 [ib][300][96]
#define O_GA1   1536000     // 307200 each, [ib][n][d] fp32
#define O_GB1   1843200
#define O_GA2   2150400
#define O_GB2   2457600
#define O_ADJB  2764800     // bf16 [ib][320][320]
#define O_XTB   6041600     // bf16 [ib][96][320]
#define O_H1B   7024640     // bf16 [ib][96][320]
#define O_H1VB  8007680     // bf16 [ib][300][96]
#define O_WMB   8929280     // bf16 [32][96]
#define O_IRZ   8932352     // 614400  [ib][n][32]
#define O_IH    9546752     // 307200  [ib][n][16]

__device__ __forceinline__ float sigf(float x){ return 1.0f/(1.0f+expf(-x)); }

__global__ void k_prep(const float* __restrict__ x, __hip_bfloat16* __restrict__ xtb,
                       __hip_bfloat16* __restrict__ xvb, float* __restrict__ inp,
                       __hip_bfloat16* __restrict__ h1b, const float* __restrict__ Wm,
                       __hip_bfloat16* __restrict__ Wmb){
    int idx = blockIdx.x*256 + threadIdx.x;   // (b,c,n), n fastest
    if (idx >= BB*CC*NN) return;
    if (idx < NIB*COL*(KP-NN)){               // zero K-pads of xtb/h1b
        int kk  = idx % (KP-NN);
        int col = (idx / (KP-NN)) % COL;
        int ib  = idx / ((KP-NN)*COL);
        size_t off = ((size_t)ib*COL + col)*KP + NN + kk;
        xtb[off] = __float2bfloat16(0.0f);
        h1b[off] = __float2bfloat16(0.0f);
    }
    if (idx < COO*COL){                       // Wmb[o][k] = Wm[k][o]
        int o = idx / COL, k = idx % COL;
        Wmb[o*COL + k] = __float2bfloat16(Wm[k*COO + o]);
    }
    int n = idx % NN;
    int c = (idx / NN) % CC;
    int b = idx / (NN*CC);
    const float* xp = x + ((b*CC + c)*NN + n)*TT;
    float v[TT];
    #pragma unroll
    for (int t=0;t<TT;t++) v[t] = xp[t];
    #pragma unroll
    for (int i=0;i<NCH;i++){
        float m = (v[3*i]+v[3*i+1]+v[3*i+2])*(1.0f/3.0f);
        int ib = i*BB + b;
        inp[((size_t)ib*NN + n)*CC + c] = m;
        #pragma unroll
        for (int t=0;t<3;t++){
            float val = v[3*i+t];
            int col = c*3 + t;
            xtb[((size_t)ib*COL + col)*KP + n] = __float2bfloat16(val);
            xvb[((size_t)ib*NN + n)*COL + col] = __float2bfloat16(val);
        }
    }
}

__global__ void k_iproj(const float* __restrict__ inp,
                        const float* __restrict__ W_rz, const float* __restrict__ b_rz,
                        const float* __restrict__ W_h,  const float* __restrict__ b_h,
                        float* __restrict__ irz, float* __restrict__ ih){
    int idx = blockIdx.x*256 + threadIdx.x;
    if (idx >= NCH*BB*NN*48) return;
    int j    = idx % 48;
    int rowg = idx / 48;                       // ib*NN + n
    const float* ip = inp + (size_t)rowg*CC;
    float a0=0.f,a1=0.f,a2=0.f,a3=0.f;
    if (j < 32){
        #pragma unroll
        for (int k=0;k<32;k+=4){
            a0 += ip[k  ]*W_rz[(k  )*32+j];
            a1 += ip[k+1]*W_rz[(k+1)*32+j];
            a2 += ip[k+2]*W_rz[(k+2)*32+j];
            a3 += ip[k+3]*W_rz[(k+3)*32+j];
        }
        irz[(size_t)rowg*32 + j] = a0+a1+a2+a3 + b_rz[j];
    } else {
        int d = j-32;
        #pragma unroll
        for (int k=0;k<32;k+=4){
            a0 += ip[k  ]*W_h[(k  )*DHD+d];
            a1 += ip[k+1]*W_h[(k+1)*DHD+d];
            a2 += ip[k+2]*W_h[(k+2)*DHD+d];
            a3 += ip[k+3]*W_h[(k+3)*DHD+d];
        }
        ih[(size_t)rowg*DHD + d] = a0+a1+a2+a3 + b_h[d];
    }
}

// fused GRU: pure-shuffle, no LDS, no barriers (validated round 14)
__global__ __launch_bounds__(64) void k_gru_all(
        const float* __restrict__ stnf, const float* __restrict__ W_s2d,
        const float* __restrict__ b_s2d,
        const float* __restrict__ irz, const float* __restrict__ ih,
        const float* __restrict__ W_rz, const float* __restrict__ W_h,
        const float* __restrict__ Wc1,  const float* __restrict__ Wc2,
        float* __restrict__ ga1, float* __restrict__ gb1,
        float* __restrict__ ga2, float* __restrict__ gb2){
    int row = blockIdx.x;          // b*NN + n
    int n   = row % NN;
    int tid = threadIdx.x;         // 0..63
    int d   = tid & 15;
    float wst[16];
    if (tid < 32){
        #pragma unroll
        for (int k=0;k<16;k++) wst[k] = W_rz[(32+k)*32 + tid];
    } else if (tid < 48){
        #pragma unroll
        for (int k=0;k<16;k++) wst[k] = W_h[(32+k)*DHD + d];
    } else {
        #pragma unroll
        for (int k=0;k<16;k++) wst[k] = 0.0f;
    }
    float wpj[16];
    {
        int which = tid >> 4;
        const float* W = (which < 2) ? Wc1 : Wc2;
        int off = (which & 1) ? 16*DHD : 0;
        #pragma unroll
        for (int k=0;k<16;k++) wpj[k] = W[off + k*DHD + d];
    }
    float st = b_s2d[d];
    {
        const float* srow = stnf + n*STF;
        #pragma unroll
        for (int k=0;k<STF;k++) st += srow[k]*W_s2d[k*DHD + d];
    }
    for (int i=0;i<NCH;i++){
        size_t rowg = (size_t)i*BB*NN + row;
        float ibase = (tid < 32) ? irz[rowg*32 + tid]
                    : (tid < 48) ? ih[rowg*DHD + d] : 0.0f;
        float acc = ibase;
        #pragma unroll
        for (int k=0;k<16;k++) acc += __shfl(st, k) * wst[k];
        float rz = sigf(acc);
        float acc2 = ibase;
        #pragma unroll
        for (int k=0;k<16;k++) acc2 += __shfl(rz, k) * __shfl(st, k) * wst[k];
        float hh = tanhf(acc2);
        float z  = __shfl(rz, 16 + d);
        float hd = __shfl(hh, 32 + d);
        st = z*st + (1.0f - z)*hd;
        float hs = fmaxf(st, 0.0f);
        float acc3 = 0.0f;
        #pragma unroll
        for (int k=0;k<16;k++) acc3 += __shfl(hs, k) * wpj[k];
        int which = tid >> 4;
        float* dst = (which==0)? ga1 : (which==1)? gb1 : (which==2)? ga2 : gb2;
        dst[rowg*DHD + d] = acc3;
    }
}

// grid = NIB*ATILES. Scores to LDS, then WIDE (short8, 16B/lane) coalesced stores.
__global__ __launch_bounds__(256) void k_adj(
        const float* __restrict__ ga1, const float* __restrict__ gb1,
        const float* __restrict__ ga2, const float* __restrict__ gb2,
        const float* __restrict__ bfc2_1, const float* __restrict__ wfc1_1, const float* __restrict__ bfc1_1,
        const float* __restrict__ bfc2_2, const float* __restrict__ wfc1_2, const float* __restrict__ bfc1_2,
        __hip_bfloat16* __restrict__ adjb){
    int tile = blockIdx.x % ATILES;
    int ib   = blockIdx.x / ATILES;
    int v0 = tile * 8;
    int tid = threadIdx.x;  // 256
    __shared__ float a1[8][16], a2[8][16];
    __shared__ float w1[16], w2[16];
    __shared__ float sc[8][KP];          // 10 KB
    if (tid < 16) w1[tid] = wfc1_1[tid];
    else if (tid < 32) w2[tid-16] = wfc1_2[tid-16];
    {
        int vl = tid >> 5, which = (tid >> 4) & 1, k = tid & 15;
        int v = v0 + vl;
        float val = 0.0f;
        if (v < NN)
            val = which ? (ga2[((size_t)ib*NN+v)*DHD + k] + bfc2_2[k])
                        : (ga1[((size_t)ib*NN+v)*DHD + k] + bfc2_1[k]);
        if (which) a2[vl][k] = val; else a1[vl][k] = val;
    }
    float B1 = bfc1_1[0], B2 = bfc1_2[0];
    __syncthreads();
    int vl = tid >> 5;                   // row group 0..7
    int lw = tid & 31;
    int v  = v0 + vl;
    #pragma unroll
    for (int j=0;j<10;j++){
        int w = lw + 32*j;
        float res = 0.0f;
        if (v < NN && w < NN){
            const float4* p1 = (const float4*)(gb1 + ((size_t)ib*NN + w)*DHD);
            const float4* p2 = (const float4*)(gb2 + ((size_t)ib*NN + w)*DHD);
            float4 A[4], Bv[4];
            #pragma unroll
            for (int q=0;q<4;q++){ A[q]=p1[q]; Bv[q]=p2[q]; }
            const float* g1 = (const float*)A;
            const float* g2 = (const float*)Bv;
            float s = B1, m = B2;
            #pragma unroll
            for (int k=0;k<16;k++){
                s += fmaxf(a1[vl][k] + g1[k], 0.0f)*w1[k];
                m += fmaxf(a2[vl][k] + g2[k], 0.0f)*w2[k];
            }
            res = s * sigf(m);
        }
        sc[vl][w] = res;
    }
    __syncthreads();
    // store phase: 8 rows x 40 chunks of 8 bf16 (16 B per lane, coalesced)
    for (int idx = tid; idx < 8*40; idx += 256){
        int row = idx / 40, ch = idx % 40;
        short8 pack;
        #pragma unroll
        for (int e=0;e<8;e++){
            __hip_bfloat16 bv = __float2bfloat16(sc[row][ch*8+e]);
            pack[e] = *(short*)&bv;
        }
        *(short8*)(adjb + ((size_t)ib*KP + v0+row)*KP + ch*8) = pack;
    }
}

// MFMA conv core: block = 4 waves, output tile 32 v-rows x 96 cols, K=320.
__device__ __forceinline__ void conv_mfma_tile(const __hip_bfloat16* __restrict__ adjb,
                                               const __hip_bfloat16* __restrict__ Hb,
                                               int ib, int v0, int wave, int lane,
                                               f32x4& acc0, f32x4& acc1, f32x4& acc2){
    int l15 = lane & 15, lk = lane >> 4;
    int wrow = (wave & 1) * 16;
    int wcol = (wave >> 1) * 48;
    const short8* Ap  = (const short8*)(adjb + ((size_t)ib*KP + v0 + wrow + l15)*KP + 8*lk);
    const short8* Bp0 = (const short8*)(Hb   + ((size_t)ib*COL + wcol +  0 + l15)*KP + 8*lk);
    const short8* Bp1 = (const short8*)(Hb   + ((size_t)ib*COL + wcol + 16 + l15)*KP + 8*lk);
    const short8* Bp2 = (const short8*)(Hb   + ((size_t)ib*COL + wcol + 32 + l15)*KP + 8*lk);
    #pragma unroll 2
    for (int kk=0; kk<KP/32; kk++){
        short8 a = Ap[kk*4];
        acc0 = __builtin_amdgcn_mfma_f32_16x16x32_bf16(a, Bp0[kk*4], acc0, 0, 0, 0);
        acc1 = __builtin_amdgcn_mfma_f32_16x16x32_bf16(a, Bp1[kk*4], acc1, 0, 0, 0);
        acc2 = __builtin_amdgcn_mfma_f32_16x16x32_bf16(a, Bp2[kk*4], acc2, 0, 0, 0);
    }
}

// grid = NIB*10. h1 = 0.05*x + 0.95*(adj @ x)
__global__ __launch_bounds__(256) void k_conv1(const __hip_bfloat16* __restrict__ adjb,
                                               const __hip_bfloat16* __restrict__ xtb,
                                               const __hip_bfloat16* __restrict__ xvb,
                                               __hip_bfloat16* __restrict__ h1b,
                                               __hip_bfloat16* __restrict__ h1vb){
    int ib = blockIdx.x / 10;
    int v0 = (blockIdx.x % 10) * 32;
    int tid = threadIdx.x;
    int wave = tid >> 6, lane = tid & 63;
    int l15 = lane & 15, lk = lane >> 4;
    int wrow = (wave & 1) * 16;
    int wcol = (wave >> 1) * 48;
    __shared__ float hbuf[COL][33];
    f32x4 acc0 = {0.f,0.f,0.f,0.f}, acc1 = acc0, acc2 = acc0;
    conv_mfma_tile(adjb, xtb, ib, v0, wave, lane, acc0, acc1, acc2);
    f32x4 accs[3] = {acc0, acc1, acc2};
    #pragma unroll
    for (int t=0;t<3;t++){
        int col = wcol + t*16 + l15;
        #pragma unroll
        for (int r=0;r<4;r++){
            int vloc = wrow + lk*4 + r;
            int v = v0 + vloc;
            float xval = (v < NN) ? __bfloat162float(xvb[((size_t)ib*NN + v)*COL + col]) : 0.0f;
            hbuf[col][vloc] = ALPHAF*xval + (1.0f-ALPHAF)*accs[t][r];
        }
    }
    __syncthreads();
    for (int idx = tid; idx < COL*32; idx += 256){
        int col = idx >> 5, vloc = idx & 31;
        int v = v0 + vloc;
        if (v < NN)
            h1b[((size_t)ib*COL + col)*KP + v] = __float2bfloat16(hbuf[col][vloc]);
    }
    for (int idx = tid; idx < 32*COL; idx += 256){
        int vloc = idx / COL, col = idx % COL;
        int v = v0 + vloc;
        if (v < NN)
            h1vb[((size_t)ib*NN + v)*COL + col] = __float2bfloat16(hbuf[col][vloc]);
    }
}

// grid = NIB*10. h2 conv + MLP as MFMA
__global__ __launch_bounds__(256) void k_conv2_mlp(const __hip_bfloat16* __restrict__ adjb,
                                                   const __hip_bfloat16* __restrict__ h1b,
                                                   const __hip_bfloat16* __restrict__ xvb,
                                                   const __hip_bfloat16* __restrict__ h1vb,
                                                   const __hip_bfloat16* __restrict__ Wmb,
                                                   const float* __restrict__ bmlp,
                                                   float* __restrict__ out){
    int ib = blockIdx.x / 10;
    int v0 = (blockIdx.x % 10) * 32;
    int b  = ib % BB, chunk = ib / BB;
    int tid = threadIdx.x;
    int wave = tid >> 6, lane = tid & 63;
    int l15 = lane & 15, lk = lane >> 4;
    int wrow = (wave & 1) * 16;
    int wcol = (wave >> 1) * 48;
    __shared__ ushort_t hst[3][3][32][HS];
    for (int idx = tid; idx < 2*32*COL; idx += 256){
        int which = idx / (32*COL);
        int r     = idx % (32*COL);
        int vloc  = r / COL, col = r % COL;
        int v = v0 + vloc;
        int c = col/3, t = col%3;
        ushort_t val = 0;
        if (v < NN){
            const ushort_t* src = (const ushort_t*)(which ? h1vb : xvb);
            val = src[((size_t)ib*NN + v)*COL + col];
        }
        hst[t][which][vloc][c] = val;
    }
    f32x4 acc0 = {0.f,0.f,0.f,0.f}, acc1 = acc0, acc2 = acc0;
    conv_mfma_tile(adjb, h1b, ib, v0, wave, lane, acc0, acc1, acc2);
    f32x4 accs[3] = {acc0, acc1, acc2};
    #pragma unroll
    for (int tt=0;tt<3;tt++){
        int col = wcol + tt*16 + l15;
        int c = col/3, t = col%3;
        #pragma unroll
        for (int r=0;r<4;r++){
            int vloc = wrow + lk*4 + r;
            int v = v0 + vloc;
            float val = 0.0f;
            if (v < NN){
                float xval = __bfloat162float(xvb[((size_t)ib*NN + v)*COL + col]);
                val = ALPHAF*xval + (1.0f-ALPHAF)*accs[tt][r];
            }
            __hip_bfloat16 bv = __float2bfloat16(val);
            hst[t][2][vloc][c] = *(ushort_t*)&bv;
        }
    }
    __syncthreads();
    #pragma unroll
    for (int j=0;j<3;j++){
        int tile = wave + 4*j;
        int t  = tile >> 2;
        int vt = (tile & 3) >> 1;
        int ot = tile & 1;
        f32x4 acc = {0.f,0.f,0.f,0.f};
        #pragma unroll
        for (int d=0;d<3;d++){
            short8 a = *(const short8*)&hst[t][d][vt*16 + l15][8*lk];
            short8 bfr = *(const short8*)(Wmb + ((size_t)(ot*16 + l15))*COL + d*32 + 8*lk);
            acc = __builtin_amdgcn_mfma_f32_16x16x32_bf16(a, bfr, acc, 0, 0, 0);
        }
        int o = ot*16 + l15;
        float bias = bmlp[o];
        #pragma unroll
        for (int r=0;r<4;r++){
            int v = v0 + vt*16 + lk*4 + r;
            if (v < NN)
                out[(((size_t)b*COO + o)*NN + v)*TT + chunk*3 + t] = acc[r] + bias;
        }
    }
}

extern "C" void kernel_launch(void* const* d_in, const int* in_sizes, int n_in,
                              void* d_out, int out_size, void* d_ws, size_t ws_size,
                              hipStream_t stream){
    const float* x     = (const float*)d_in[0];
    const float* stnf  = (const float*)d_in[1];
    const float* W_s2d = (const float*)d_in[2];
    const float* b_s2d = (const float*)d_in[3];
    const float* W_rz  = (const float*)d_in[4];
    const float* b_rz  = (const float*)d_in[5];
    const float* W_h   = (const float*)d_in[6];
    const float* b_h   = (const float*)d_in[7];
    const float* Wc1f2 = (const float*)d_in[8];
    const float* bc1f2 = (const float*)d_in[9];
    const float* Wc1f1 = (const float*)d_in[10];
    const float* bc1f1 = (const float*)d_in[11];
    const float* Wc2f2 = (const float*)d_in[12];
    const float* bc2f2 = (const float*)d_in[13];
    const float* Wc2f1 = (const float*)d_in[14];
    const float* bc2f1 = (const float*)d_in[15];
    const float* W_mlp = (const float*)d_in[16];
    const float* b_mlp = (const float*)d_in[17];
    float* out = (float*)d_out;
    float* ws  = (float*)d_ws;

    float* inp = ws + O_INP;
    float* ga1 = ws + O_GA1;
    float* gb1 = ws + O_GB1;
    float* ga2 = ws + O_GA2;
    float* gb2 = ws + O_GB2;
    float* irz = ws + O_IRZ;
    float* ih  = ws + O_IH;
    __hip_bfloat16* xvb  = (__hip_bfloat16*)(ws + O_XVB);
    __hip_bfloat16* adjb = (__hip_bfloat16*)(ws + O_ADJB);
    __hip_bfloat16* xtb  = (__hip_bfloat16*)(ws + O_XTB);
    __hip_bfloat16* h1b  = (__hip_bfloat16*)(ws + O_H1B);
    __hip_bfloat16* h1vb = (__hip_bfloat16*)(ws + O_H1VB);
    __hip_bfloat16* Wmb  = (__hip_bfloat16*)(ws + O_WMB);

    hipLaunchKernelGGL(k_prep, dim3(600), dim3(256), 0, stream, x, xtb, xvb, inp, h1b, W_mlp, Wmb);
    hipLaunchKernelGGL(k_iproj, dim3(3600), dim3(256), 0, stream,
                       inp, W_rz, b_rz, W_h, b_h, irz, ih);
    hipLaunchKernelGGL(k_gru_all, dim3(BB*NN), dim3(64), 0, stream,
                       stnf, W_s2d, b_s2d, irz, ih, W_rz, W_h, Wc1f2, Wc2f2,
                       ga1, gb1, ga2, gb2);
    hipLaunchKernelGGL(k_adj, dim3(NIB*ATILES), dim3(256), 0, stream,
                       ga1, gb1, ga2, gb2,
                       bc1f2, Wc1f1, bc1f1, bc2f2, Wc2f1, bc2f1, adjb);
    hipLaunchKernelGGL(k_conv1, dim3(NIB*10), dim3(256), 0, stream,
                       adjb, xtb, xvb, h1b, h1vb);
    hipLaunchKernelGGL(k_conv2_mlp, dim3(NIB*10), dim3(256), 0, stream,
                       adjb, h1b, xvb, h1vb, Wmb, b_mlp, out);
}